// Round 3
// baseline (3197.862 us; speedup 1.0000x reference)
//
#include <hip/hip_runtime.h>

typedef unsigned short u16;
typedef __attribute__((ext_vector_type(8))) short short8;   // 8 bf16 = 4 VGPRs (MFMA A/B frag)
typedef __attribute__((ext_vector_type(4))) float f32x4;    // MFMA C/D frag

#define T_SEQ 8192
#define DDIM 1024
#define BB 4
#define MM (BB * T_SEQ)      // 32768
#define NC 128               // chunks along T
#define CHUNK (T_SEQ / NC)   // 64
#define CHAINS (BB * DDIM)   // 4096

// ---------- helpers ----------
__device__ __forceinline__ float bf_lo(unsigned p) {
    union { unsigned u; float f; } v; v.u = p << 16; return v.f;
}
__device__ __forceinline__ float bf_hi(unsigned p) {
    union { unsigned u; float f; } v; v.u = p & 0xffff0000u; return v.f;
}
__device__ __forceinline__ float bf_u16(u16 p) {
    union { unsigned u; float f; } v; v.u = ((unsigned)p) << 16; return v.f;
}
__device__ __forceinline__ u16 f2bf(float f) {
    union { unsigned u; float f; } v; v.f = f;
    unsigned r = v.u + 0x7fffu + ((v.u >> 16) & 1u);   // RNE
    return (u16)(r >> 16);
}
__device__ __forceinline__ float sigm(float z) {
    return __builtin_amdgcn_rcpf(1.0f + __expf(-z));
}
__device__ __forceinline__ void gld16(const u16* g, u16* l) {
    __builtin_amdgcn_global_load_lds((const __attribute__((address_space(1))) void*)g,
                                     (__attribute__((address_space(3))) void*)l, 16, 0, 0);
}

// ---------- K1: fused fp32 -> bf16 convert for x, W_in, W_gate ----------
#define N4X (MM * DDIM / 4)      // 8388608 float4s
#define N4W (DDIM * DDIM / 4)    // 262144 float4s
__global__ __launch_bounds__(256) void cvt_all(const float* __restrict__ x,
                                               const float* __restrict__ Wi,
                                               const float* __restrict__ Wg,
                                               u16* __restrict__ Xb,
                                               u16* __restrict__ Wib,
                                               u16* __restrict__ Wgb) {
    int i = blockIdx.x * 256 + threadIdx.x;   // global float4 index
    const float* src; u16* dst; int j;
    if (i < N4X)            { src = x;  dst = Xb;  j = i; }
    else if (i < N4X + N4W) { src = Wi; dst = Wib; j = i - N4X; }
    else                    { src = Wg; dst = Wgb; j = i - N4X - N4W; }
    float4 v = ((const float4*)src)[j];
    ushort4 o;
    o.x = f2bf(v.x); o.y = f2bf(v.y); o.z = f2bf(v.z); o.w = f2bf(v.w);
    ((ushort4*)dst)[j] = o;
}

// ---------- K2: fused bf16 GEMM + gating epilogue ----------
// 512 threads = 8 waves; waves 0-3 hold IG accs, waves 4-7 RG accs for the
// SAME (t,d) tile. Epilogue: RG waves compute s = -8*softplus(lam)*sigm(rg),
// store S (bf16) + exchange s via LDS; IG waves compute xb = beta*sigm(ig)*x,
// store XB (bf16). Scans then never touch raw gates or fp32 x.
__global__ __launch_bounds__(512, 4)
void gemm_fused(const u16* __restrict__ X, const u16* __restrict__ Wi,
                const u16* __restrict__ Wg, const float* __restrict__ b_in,
                const float* __restrict__ b_gate, const float* __restrict__ lam,
                u16* __restrict__ Sg, u16* __restrict__ XBg) {
    const int b = blockIdx.x;           // 0..2047
    const int xcd = b & 7;
    const int r = b >> 3;               // 0..255
    const int n_tile = r & 7;           // N fastest within an XCD
    const int m_tile = xcd * 32 + (r >> 3);   // XCD i owns M-tiles [32i,32i+32)
    const int tN0 = n_tile * 128;
    const int tM0 = m_tile * 128;

    const int tid = threadIdx.x;
    const int lane = tid & 63;
    const int w = tid >> 6;             // 0..7
    const int gate = w >> 2;            // 0: IG waves, 1: RG waves
    const int wq = w & 3;
    const int wm = wq >> 1, wn = wq & 1;

    __shared__ u16 lA[128 * 32];
    __shared__ u16 lBi[128 * 32];
    __shared__ u16 lBg[128 * 32];
    __shared__ u16 ex[4 * 4 * 4 * 64];  // 8KB epilogue s-exchange

    const u16* gA  = X  + (size_t)(tM0 + (tid >> 2)) * DDIM + (tid & 3) * 8;
    const u16* gBi = Wi + (size_t)(tN0 + (tid >> 2)) * DDIM + (tid & 3) * 8;
    const u16* gBg = Wg + (size_t)(tN0 + (tid >> 2)) * DDIM + (tid & 3) * 8;
    u16* lA0  = &lA[tid * 8];
    u16* lBi0 = &lBi[tid * 8];
    u16* lBg0 = &lBg[tid * 8];

    f32x4 acc[4][4] = {};
    const int lm = lane & 15;
    const int q8 = (lane >> 4) * 8;
    const u16* lB = gate ? lBg : lBi;   // wave-uniform select

    for (int k0 = 0; k0 < DDIM; k0 += 32) {
        __syncthreads();
        gld16(gA, lA0);
        gld16(gBi, lBi0);
        gld16(gBg, lBg0);
        gA += 32; gBi += 32; gBg += 32;
        __syncthreads();

        short8 af[4], bfr[4];
#pragma unroll
        for (int i = 0; i < 4; i++)
            af[i] = *(const short8*)&lA[(wm * 64 + i * 16 + lm) * 32 + q8];
#pragma unroll
        for (int j = 0; j < 4; j++)
            bfr[j] = *(const short8*)&lB[(wn * 64 + j * 16 + lm) * 32 + q8];
#pragma unroll
        for (int i = 0; i < 4; i++)
#pragma unroll
            for (int j = 0; j < 4; j++)
                acc[i][j] = __builtin_amdgcn_mfma_f32_16x16x32_bf16(af[i], bfr[j], acc[i][j], 0, 0, 0);
    }

    // ---- epilogue: C/D layout col=lane&15, row=(lane>>4)*4+reg ----
    const int r0 = (lane >> 4) << 2;
    const int cb = lane & 15;
    for (int j = 0; j < 4; j++) {
        __syncthreads();
        const int colg = tN0 + wn * 64 + j * 16 + cb;
        if (gate) {                     // RG waves: s = nsp*sigm(rg)
            const float bj = b_gate[colg];
            const float nsp = -8.0f * log1pf(__expf(lam[colg]));
#pragma unroll
            for (int i = 0; i < 4; i++) {
                const int rowb = tM0 + wm * 64 + i * 16 + r0;
#pragma unroll
                for (int rr = 0; rr < 4; rr++) {
                    float s = nsp * sigm(acc[i][j][rr] + bj);
                    u16 sb = f2bf(s);
                    Sg[(size_t)(rowb + rr) * DDIM + colg] = sb;
                    ex[((wq * 4 + i) * 4 + rr) * 64 + lane] = sb;
                }
            }
        }
        __syncthreads();
        if (!gate) {                    // IG waves: xb = beta*sigm(ig)*x
            const float bj = b_in[colg];
#pragma unroll
            for (int i = 0; i < 4; i++) {
                const int rowb = tM0 + wm * 64 + i * 16 + r0;
#pragma unroll
                for (int rr = 0; rr < 4; rr++) {
                    float s = bf_u16(ex[((wq * 4 + i) * 4 + rr) * 64 + lane]);
                    float a2 = __expf(2.0f * s);
                    float be = sqrtf(1.0f - a2 + 1e-6f);
                    float p = sigm(acc[i][j][rr] + bj);
                    float xv = bf_u16(X[(size_t)(rowb + rr) * DDIM + colg]);
                    XBg[(size_t)(rowb + rr) * DDIM + colg] = f2bf(be * p * xv);
                }
            }
        }
    }
}

// ---------- K3: pass1 — per-chunk aggregates (light: 1 exp + 2 fma / elem) ----------
__global__ __launch_bounds__(256)
void scan_pass1(const u16* __restrict__ S, const u16* __restrict__ XB,
                float* __restrict__ AggA, float* __restrict__ AggB) {
    const int c = blockIdx.x, dblk = blockIdx.y, bq = blockIdx.z;
    const int d0 = dblk * 512 + threadIdx.x * 2;
    size_t base = ((size_t)(bq * T_SEQ + c * CHUNK)) * DDIM + d0;

    float A0 = 1.0f, B0 = 0.0f, A1 = 1.0f, B1 = 0.0f;
#pragma unroll 8
    for (int t = 0; t < CHUNK; t++) {
        unsigned sp = *(const unsigned*)(S + base);
        unsigned xp = *(const unsigned*)(XB + base);
        float a0 = __expf(bf_lo(sp));
        float a1 = __expf(bf_hi(sp));
        B0 = fmaf(a0, B0, bf_lo(xp)); A0 *= a0;
        B1 = fmaf(a1, B1, bf_hi(xp)); A1 *= a1;
        base += DDIM;
    }
    const int chain = bq * DDIM + d0;
    float2 av; av.x = A0; av.y = A1;
    float2 bv; bv.x = B0; bv.y = B1;
    *(float2*)(AggA + (size_t)c * CHAINS + chain) = av;
    *(float2*)(AggB + (size_t)c * CHAINS + chain) = bv;
}

// ---------- K4: pass2 — serial scan over NC chunk aggregates per chain ----------
__global__ __launch_bounds__(256)
void scan_pass2(const float* __restrict__ AggA, const float* __restrict__ AggB,
                float* __restrict__ H0) {
    const int chain = blockIdx.x * 256 + threadIdx.x;   // 4096 chains
    float p = 0.0f;
#pragma unroll 8
    for (int c = 0; c < NC; c++) {
        H0[(size_t)c * CHAINS + chain] = p;
        p = AggA[(size_t)c * CHAINS + chain] * p + AggB[(size_t)c * CHAINS + chain];
    }
}

// ---------- K5: pass3 — apply chunk prefix, write h ----------
__global__ __launch_bounds__(256)
void scan_pass3(const u16* __restrict__ S, const u16* __restrict__ XB,
                const float* __restrict__ H0, float* __restrict__ out) {
    const int c = blockIdx.x, dblk = blockIdx.y, bq = blockIdx.z;
    const int d0 = dblk * 512 + threadIdx.x * 2;
    size_t base = ((size_t)(bq * T_SEQ + c * CHUNK)) * DDIM + d0;
    const int chain = bq * DDIM + d0;

    float2 h = *(const float2*)(H0 + (size_t)c * CHAINS + chain);
#pragma unroll 8
    for (int t = 0; t < CHUNK; t++) {
        unsigned sp = *(const unsigned*)(S + base);
        unsigned xp = *(const unsigned*)(XB + base);
        float a0 = __expf(bf_lo(sp));
        float a1 = __expf(bf_hi(sp));
        h.x = fmaf(a0, h.x, bf_lo(xp));
        h.y = fmaf(a1, h.y, bf_hi(xp));
        *(float2*)(out + base) = h;
        base += DDIM;
    }
}

// ---------- launch ----------
extern "C" void kernel_launch(void* const* d_in, const int* in_sizes, int n_in,
                              void* d_out, int out_size, void* d_ws, size_t ws_size,
                              hipStream_t stream) {
    const float* x   = (const float*)d_in[0];
    const float* Win = (const float*)d_in[1];
    const float* bin = (const float*)d_in[2];
    const float* Wg  = (const float*)d_in[3];
    const float* bg  = (const float*)d_in[4];
    const float* lam = (const float*)d_in[5];
    float* out = (float*)d_out;

    // ws layout (MiB): Wi_bf 0..2, Wg_bf 2..4, S 4..68, XB 68..132,
    // AggA 132..134, AggB 134..136, H0 136..138  (= 138 MiB)
    char* w = (char*)d_ws;
    u16* Wi_bf  = (u16*)(w);
    u16* Wg_bf  = (u16*)(w + (size_t)(2) * 1024 * 1024);
    u16* Sg     = (u16*)(w + (size_t)(4) * 1024 * 1024);
    u16* XBg    = (u16*)(w + (size_t)(68) * 1024 * 1024);
    float* AggA = (float*)(w + (size_t)(132) * 1024 * 1024);
    float* AggB = (float*)(w + (size_t)(134) * 1024 * 1024);
    float* H0   = (float*)(w + (size_t)(136) * 1024 * 1024);

    // x_bf16 staged in first 64 MiB of d_out (read by GEMM main loop AND
    // epilogue; dead after GEMM; pass3 then overwrites d_out with h)
    u16* Xbf = (u16*)d_out;

    // K1: one fused convert (x + both W)
    cvt_all<<<dim3((N4X + 2 * N4W) / 256), dim3(256), 0, stream>>>(
        x, Win, Wg, Xbf, Wi_bf, Wg_bf);

    // K2: fused gate GEMM + gating epilogue, XCD-swizzled
    gemm_fused<<<dim3((DDIM / 128) * (MM / 128)), dim3(512), 0, stream>>>(
        Xbf, Wi_bf, Wg_bf, bin, bg, lam, Sg, XBg);

    // K3-K5: chunked scan over compact bf16 (S, XB)
    scan_pass1<<<dim3(NC, 2, BB), dim3(256), 0, stream>>>(Sg, XBg, AggA, AggB);
    scan_pass2<<<dim3(CHAINS / 256), dim3(256), 0, stream>>>(AggA, AggB, H0);
    scan_pass3<<<dim3(NC, 2, BB), dim3(256), 0, stream>>>(Sg, XBg, H0, out);
}

// Round 4
// 515.603 us; speedup vs baseline: 6.2022x; 6.2022x over previous
//
#include <hip/hip_runtime.h>

typedef unsigned short u16;
typedef __attribute__((ext_vector_type(8))) short short8;   // 8 bf16 = 4 VGPRs (MFMA A/B frag)
typedef __attribute__((ext_vector_type(4))) float f32x4;    // MFMA C/D frag

#define T_SEQ 8192
#define DDIM 1024
#define BB 4
#define MM (BB * T_SEQ)      // 32768
#define NC 128               // chunks along T
#define CHUNK (T_SEQ / NC)   // 64
#define CHAINS (BB * DDIM)   // 4096

// ---------- helpers ----------
__device__ __forceinline__ float bf_lo(unsigned p) {
    union { unsigned u; float f; } v; v.u = p << 16; return v.f;
}
__device__ __forceinline__ float bf_hi(unsigned p) {
    union { unsigned u; float f; } v; v.u = p & 0xffff0000u; return v.f;
}
__device__ __forceinline__ float bf_u16(u16 p) {
    union { unsigned u; float f; } v; v.u = ((unsigned)p) << 16; return v.f;
}
__device__ __forceinline__ u16 f2bf(float f) {
    union { unsigned u; float f; } v; v.f = f;
    unsigned r = v.u + 0x7fffu + ((v.u >> 16) & 1u);   // RNE
    return (u16)(r >> 16);
}
__device__ __forceinline__ float sigm(float z) {
    return __builtin_amdgcn_rcpf(1.0f + __expf(-z));
}
__device__ __forceinline__ void gld16(const u16* g, u16* l) {
    __builtin_amdgcn_global_load_lds((const __attribute__((address_space(1))) void*)g,
                                     (__attribute__((address_space(3))) void*)l, 16, 0, 0);
}

// ---------- K1: fused fp32 -> bf16 convert for x, W_in, W_gate ----------
#define N4X (MM * DDIM / 4)      // 8388608 float4s
#define N4W (DDIM * DDIM / 4)    // 262144 float4s
__global__ __launch_bounds__(256) void cvt_all(const float* __restrict__ x,
                                               const float* __restrict__ Wi,
                                               const float* __restrict__ Wg,
                                               u16* __restrict__ Xb,
                                               u16* __restrict__ Wib,
                                               u16* __restrict__ Wgb) {
    int i = blockIdx.x * 256 + threadIdx.x;   // global float4 index
    const float* src; u16* dst; int j;
    if (i < N4X)            { src = x;  dst = Xb;  j = i; }
    else if (i < N4X + N4W) { src = Wi; dst = Wib; j = i - N4X; }
    else                    { src = Wg; dst = Wgb; j = i - N4X - N4W; }
    float4 v = ((const float4*)src)[j];
    ushort4 o;
    o.x = f2bf(v.x); o.y = f2bf(v.y); o.z = f2bf(v.z); o.w = f2bf(v.w);
    ((ushort4*)dst)[j] = o;
}

// ---------- K2: fused bf16 GEMM + gating epilogue ----------
// 512 threads = 8 waves; waves 0-3 hold IG accs, waves 4-7 RG accs for the
// SAME (t,d) tile. Epilogue: RG waves compute s = -8*softplus(lam)*sigm(rg),
// store S (bf16) + exchange s via LDS; IG waves compute xb = beta*sigm(ig)*x,
// store XB (bf16). Scans then never touch raw gates or fp32 x.
// NOTE: epilogue j-loop MUST be unrolled — a runtime j makes acc[i][j][rr]
// dynamically indexed -> acc demoted to scratch -> 14 GB spill traffic (R3).
__global__ __launch_bounds__(512, 4)
void gemm_fused(const u16* __restrict__ X, const u16* __restrict__ Wi,
                const u16* __restrict__ Wg, const float* __restrict__ b_in,
                const float* __restrict__ b_gate, const float* __restrict__ lam,
                u16* __restrict__ Sg, u16* __restrict__ XBg) {
    const int b = blockIdx.x;           // 0..2047
    const int xcd = b & 7;
    const int r = b >> 3;               // 0..255
    const int n_tile = r & 7;           // N fastest within an XCD
    const int m_tile = xcd * 32 + (r >> 3);   // XCD i owns M-tiles [32i,32i+32)
    const int tN0 = n_tile * 128;
    const int tM0 = m_tile * 128;

    const int tid = threadIdx.x;
    const int lane = tid & 63;
    const int w = tid >> 6;             // 0..7
    const int gate = w >> 2;            // 0: IG waves, 1: RG waves
    const int wq = w & 3;
    const int wm = wq >> 1, wn = wq & 1;

    __shared__ u16 lA[128 * 32];
    __shared__ u16 lBi[128 * 32];
    __shared__ u16 lBg[128 * 32];
    __shared__ u16 ex[4 * 4 * 4 * 64];  // 8KB epilogue s-exchange

    const u16* gA  = X  + (size_t)(tM0 + (tid >> 2)) * DDIM + (tid & 3) * 8;
    const u16* gBi = Wi + (size_t)(tN0 + (tid >> 2)) * DDIM + (tid & 3) * 8;
    const u16* gBg = Wg + (size_t)(tN0 + (tid >> 2)) * DDIM + (tid & 3) * 8;
    u16* lA0  = &lA[tid * 8];
    u16* lBi0 = &lBi[tid * 8];
    u16* lBg0 = &lBg[tid * 8];

    f32x4 acc[4][4] = {};
    const int lm = lane & 15;
    const int q8 = (lane >> 4) * 8;
    const u16* lB = gate ? lBg : lBi;   // wave-uniform select

    for (int k0 = 0; k0 < DDIM; k0 += 32) {
        __syncthreads();
        gld16(gA, lA0);
        gld16(gBi, lBi0);
        gld16(gBg, lBg0);
        gA += 32; gBi += 32; gBg += 32;
        __syncthreads();

        short8 af[4], bfr[4];
#pragma unroll
        for (int i = 0; i < 4; i++)
            af[i] = *(const short8*)&lA[(wm * 64 + i * 16 + lm) * 32 + q8];
#pragma unroll
        for (int j = 0; j < 4; j++)
            bfr[j] = *(const short8*)&lB[(wn * 64 + j * 16 + lm) * 32 + q8];
#pragma unroll
        for (int i = 0; i < 4; i++)
#pragma unroll
            for (int j = 0; j < 4; j++)
                acc[i][j] = __builtin_amdgcn_mfma_f32_16x16x32_bf16(af[i], bfr[j], acc[i][j], 0, 0, 0);
    }

    // ---- epilogue: C/D layout col=lane&15, row=(lane>>4)*4+reg ----
    const int r0 = (lane >> 4) << 2;
    const int cb = lane & 15;
#pragma unroll
    for (int j = 0; j < 4; j++) {
        __syncthreads();
        const int colg = tN0 + wn * 64 + j * 16 + cb;
        if (gate) {                     // RG waves: s = nsp*sigm(rg)
            const float bj = b_gate[colg];
            const float nsp = -8.0f * log1pf(__expf(lam[colg]));
#pragma unroll
            for (int i = 0; i < 4; i++) {
                const int rowb = tM0 + wm * 64 + i * 16 + r0;
#pragma unroll
                for (int rr = 0; rr < 4; rr++) {
                    float s = nsp * sigm(acc[i][j][rr] + bj);
                    u16 sb = f2bf(s);
                    Sg[(size_t)(rowb + rr) * DDIM + colg] = sb;
                    ex[((wq * 4 + i) * 4 + rr) * 64 + lane] = sb;
                }
            }
        }
        __syncthreads();
        if (!gate) {                    // IG waves: xb = beta*sigm(ig)*x
            const float bj = b_in[colg];
#pragma unroll
            for (int i = 0; i < 4; i++) {
                const int rowb = tM0 + wm * 64 + i * 16 + r0;
#pragma unroll
                for (int rr = 0; rr < 4; rr++) {
                    float s = bf_u16(ex[((wq * 4 + i) * 4 + rr) * 64 + lane]);
                    float a2 = __expf(2.0f * s);
                    float be = sqrtf(1.0f - a2 + 1e-6f);
                    float p = sigm(acc[i][j][rr] + bj);
                    float xv = bf_u16(X[(size_t)(rowb + rr) * DDIM + colg]);
                    XBg[(size_t)(rowb + rr) * DDIM + colg] = f2bf(be * p * xv);
                }
            }
        }
    }
}

// ---------- K3: pass1 — per-chunk aggregates (light: 1 exp + 2 fma / elem) ----------
__global__ __launch_bounds__(256)
void scan_pass1(const u16* __restrict__ S, const u16* __restrict__ XB,
                float* __restrict__ AggA, float* __restrict__ AggB) {
    const int c = blockIdx.x, dblk = blockIdx.y, bq = blockIdx.z;
    const int d0 = dblk * 512 + threadIdx.x * 2;
    size_t base = ((size_t)(bq * T_SEQ + c * CHUNK)) * DDIM + d0;

    float A0 = 1.0f, B0 = 0.0f, A1 = 1.0f, B1 = 0.0f;
#pragma unroll 8
    for (int t = 0; t < CHUNK; t++) {
        unsigned sp = *(const unsigned*)(S + base);
        unsigned xp = *(const unsigned*)(XB + base);
        float a0 = __expf(bf_lo(sp));
        float a1 = __expf(bf_hi(sp));
        B0 = fmaf(a0, B0, bf_lo(xp)); A0 *= a0;
        B1 = fmaf(a1, B1, bf_hi(xp)); A1 *= a1;
        base += DDIM;
    }
    const int chain = bq * DDIM + d0;
    float2 av; av.x = A0; av.y = A1;
    float2 bv; bv.x = B0; bv.y = B1;
    *(float2*)(AggA + (size_t)c * CHAINS + chain) = av;
    *(float2*)(AggB + (size_t)c * CHAINS + chain) = bv;
}

// ---------- K4: pass2 — serial scan over NC chunk aggregates per chain ----------
__global__ __launch_bounds__(256)
void scan_pass2(const float* __restrict__ AggA, const float* __restrict__ AggB,
                float* __restrict__ H0) {
    const int chain = blockIdx.x * 256 + threadIdx.x;   // 4096 chains
    float p = 0.0f;
#pragma unroll 8
    for (int c = 0; c < NC; c++) {
        H0[(size_t)c * CHAINS + chain] = p;
        p = AggA[(size_t)c * CHAINS + chain] * p + AggB[(size_t)c * CHAINS + chain];
    }
}

// ---------- K5: pass3 — apply chunk prefix, write h ----------
__global__ __launch_bounds__(256)
void scan_pass3(const u16* __restrict__ S, const u16* __restrict__ XB,
                const float* __restrict__ H0, float* __restrict__ out) {
    const int c = blockIdx.x, dblk = blockIdx.y, bq = blockIdx.z;
    const int d0 = dblk * 512 + threadIdx.x * 2;
    size_t base = ((size_t)(bq * T_SEQ + c * CHUNK)) * DDIM + d0;
    const int chain = bq * DDIM + d0;

    float2 h = *(const float2*)(H0 + (size_t)c * CHAINS + chain);
#pragma unroll 8
    for (int t = 0; t < CHUNK; t++) {
        unsigned sp = *(const unsigned*)(S + base);
        unsigned xp = *(const unsigned*)(XB + base);
        float a0 = __expf(bf_lo(sp));
        float a1 = __expf(bf_hi(sp));
        h.x = fmaf(a0, h.x, bf_lo(xp));
        h.y = fmaf(a1, h.y, bf_hi(xp));
        *(float2*)(out + base) = h;
        base += DDIM;
    }
}

// ---------- launch ----------
extern "C" void kernel_launch(void* const* d_in, const int* in_sizes, int n_in,
                              void* d_out, int out_size, void* d_ws, size_t ws_size,
                              hipStream_t stream) {
    const float* x   = (const float*)d_in[0];
    const float* Win = (const float*)d_in[1];
    const float* bin = (const float*)d_in[2];
    const float* Wg  = (const float*)d_in[3];
    const float* bg  = (const float*)d_in[4];
    const float* lam = (const float*)d_in[5];
    float* out = (float*)d_out;

    // ws layout (MiB): Wi_bf 0..2, Wg_bf 2..4, S 4..68, XB 68..132,
    // AggA 132..134, AggB 134..136, H0 136..138  (= 138 MiB)
    char* w = (char*)d_ws;
    u16* Wi_bf  = (u16*)(w);
    u16* Wg_bf  = (u16*)(w + (size_t)(2) * 1024 * 1024);
    u16* Sg     = (u16*)(w + (size_t)(4) * 1024 * 1024);
    u16* XBg    = (u16*)(w + (size_t)(68) * 1024 * 1024);
    float* AggA = (float*)(w + (size_t)(132) * 1024 * 1024);
    float* AggB = (float*)(w + (size_t)(134) * 1024 * 1024);
    float* H0   = (float*)(w + (size_t)(136) * 1024 * 1024);

    // x_bf16 staged in first 64 MiB of d_out (read by GEMM main loop AND
    // epilogue; dead after GEMM; pass3 then overwrites d_out with h)
    u16* Xbf = (u16*)d_out;

    // K1: one fused convert (x + both W)
    cvt_all<<<dim3((N4X + 2 * N4W) / 256), dim3(256), 0, stream>>>(
        x, Win, Wg, Xbf, Wi_bf, Wg_bf);

    // K2: fused gate GEMM + gating epilogue, XCD-swizzled
    gemm_fused<<<dim3((DDIM / 128) * (MM / 128)), dim3(512), 0, stream>>>(
        Xbf, Wi_bf, Wg_bf, bin, bg, lam, Sg, XBg);

    // K3-K5: chunked scan over compact bf16 (S, XB)
    scan_pass1<<<dim3(NC, 2, BB), dim3(256), 0, stream>>>(Sg, XBg, AggA, AggB);
    scan_pass2<<<dim3(CHAINS / 256), dim3(256), 0, stream>>>(AggA, AggB, H0);
    scan_pass3<<<dim3(NC, 2, BB), dim3(256), 0, stream>>>(Sg, XBg, H0, out);
}